// Round 2
// baseline (1520.999 us; speedup 1.0000x reference)
//
#include <hip/hip_runtime.h>

typedef short short8 __attribute__((ext_vector_type(8)));
typedef float f32x4 __attribute__((ext_vector_type(4)));
typedef unsigned short ushort_t;

// ---- constants (problem is fixed-shape) ----
#define BB 4
#define SS 2048
#define DD 1024
#define HH 16
#define DH 64
#define KK 1024
#define MM (BB*SS)  // 8192 rows

static __device__ __forceinline__ float bf2f(ushort_t h) {
    unsigned u = ((unsigned)h) << 16;
    return __builtin_bit_cast(float, u);
}
static __device__ __forceinline__ ushort_t f2bf(float f) {
    unsigned u = __builtin_bit_cast(unsigned, f);
    u = u + 0x7fff + ((u >> 16) & 1);   // RNE
    return (ushort_t)(u >> 16);
}
// load 8 consecutive fp32, round to bf16 fragment
static __device__ __forceinline__ short8 ld_cvt8(const float* __restrict__ p) {
    const f32x4* q = (const f32x4*)p;
    f32x4 a = q[0], b = q[1];
    short8 r;
    r[0] = (short)f2bf(a[0]); r[1] = (short)f2bf(a[1]);
    r[2] = (short)f2bf(a[2]); r[3] = (short)f2bf(a[3]);
    r[4] = (short)f2bf(b[0]); r[5] = (short)f2bf(b[1]);
    r[6] = (short)f2bf(b[2]); r[7] = (short)f2bf(b[3]);
    return r;
}

// ============================================================
// Projection GEMM (fp32 A, fp32 W): C[16,64] tile = X @ W^T + b
// MODE 0: out bf16 [B,H,S,dh]; MODE 1: out bf16 [B,H,dh,S] (V^T)
// ============================================================
template<int MODE>
__global__ __launch_bounds__(64)
void proj_a32(const float* __restrict__ X,
              const float* __restrict__ W,
              const float* __restrict__ bias,
              ushort_t* __restrict__ out)
{
    const int lane = threadIdx.x;
    const int quad = lane >> 4;
    const int col  = lane & 15;
    const int n0 = blockIdx.x * 64;
    const int m0 = blockIdx.y * 16;

    const float* ap = X + (size_t)(m0 + col) * KK + quad * 8;
    const float* bp = W + (size_t)(n0 + col) * KK + quad * 8;

    f32x4 acc[4] = {};
    for (int k0 = 0; k0 < KK; k0 += 32) {
        short8 a = ld_cvt8(ap + k0);
#pragma unroll
        for (int t = 0; t < 4; ++t) {
            short8 b = ld_cvt8(bp + (size_t)t * 16 * KK + k0);
            acc[t] = __builtin_amdgcn_mfma_f32_16x16x32_bf16(a, b, acc[t], 0, 0, 0);
        }
    }

#pragma unroll
    for (int t = 0; t < 4; ++t) {
        const int n = n0 + t * 16 + col;
        const float bv = bias[n];
#pragma unroll
        for (int r = 0; r < 4; ++r) {
            const int m = m0 + quad * 4 + r;
            const float v = acc[t][r] + bv;
            int b = m >> 11, s = m & (SS - 1);
            int h = n >> 6, d = n & (DH - 1);
            size_t idx;
            if (MODE == 0)        // [B,H,S,dh]
                idx = ((size_t)(b * HH + h) * SS + s) * DH + d;
            else                  // [B,H,dh,S]  (V transposed)
                idx = ((size_t)(b * HH + h) * DH + d) * SS + s;
            out[idx] = f2bf(v);
        }
    }
}

// ============================================================
// Output projection: A bf16 [M,K], W fp32 [N,K], out fp32 [M,N]
// ============================================================
__global__ __launch_bounds__(64)
void proj_o32(const ushort_t* __restrict__ X,
              const float* __restrict__ W,
              const float* __restrict__ bias,
              float* __restrict__ out)
{
    const int lane = threadIdx.x;
    const int quad = lane >> 4;
    const int col  = lane & 15;
    const int n0 = blockIdx.x * 64;
    const int m0 = blockIdx.y * 16;

    const ushort_t* ap = X + (size_t)(m0 + col) * KK + quad * 8;
    const float*    bp = W + (size_t)(n0 + col) * KK + quad * 8;

    f32x4 acc[4] = {};
    for (int k0 = 0; k0 < KK; k0 += 32) {
        short8 a = *(const short8*)(ap + k0);
#pragma unroll
        for (int t = 0; t < 4; ++t) {
            short8 b = ld_cvt8(bp + (size_t)t * 16 * KK + k0);
            acc[t] = __builtin_amdgcn_mfma_f32_16x16x32_bf16(a, b, acc[t], 0, 0, 0);
        }
    }

#pragma unroll
    for (int t = 0; t < 4; ++t) {
        const int n = n0 + t * 16 + col;
        const float bv = bias[n];
#pragma unroll
        for (int r = 0; r < 4; ++r) {
            const int m = m0 + quad * 4 + r;
            out[(size_t)m * DD + n] = acc[t][r] + bv;
        }
    }
}

// ============================================================
// Flash attention: one wave per (b,h, 16-query tile).
// Q,K: [BH, S, 64] bf16.  VT: [BH, 64, S] bf16.  AO: [B,S,D] bf16.
// ============================================================
__global__ __launch_bounds__(64)
void attn_kernel(const ushort_t* __restrict__ Q,
                 const ushort_t* __restrict__ Km,
                 const ushort_t* __restrict__ VT,
                 ushort_t* __restrict__ AO)
{
    __shared__ alignas(16) ushort_t pbuf[16][32];

    const int lane = threadIdx.x;
    const int quad = lane >> 4;
    const int col  = lane & 15;
    const int bid  = blockIdx.x;
    const int bh   = bid >> 7;          // S/16 = 128 q-tiles per (b,h)
    const int qt   = bid & 127;
    const int q0   = qt * 16;

    const size_t qkb = (size_t)bh * SS * DH;
    const size_t vtb = (size_t)bh * DH * SS;

    const ushort_t* qp = Q + qkb + (size_t)(q0 + col) * DH + quad * 8;
    short8 aq0 = *(const short8*)(qp);
    short8 aq1 = *(const short8*)(qp + 32);

    f32x4 o[4] = {};
    float m_i[4] = {-1e30f, -1e30f, -1e30f, -1e30f};
    float l_i[4] = {};

    const int ntiles = (q0 + 16 + 31) >> 5;
    for (int tt = 0; tt < ntiles; ++tt) {
        const int kk0 = tt * 32;

        // ---- QK^T ----
        f32x4 s[2] = {};
#pragma unroll
        for (int h2 = 0; h2 < 2; ++h2) {
            const ushort_t* kp = Km + qkb + (size_t)(kk0 + h2 * 16 + col) * DH + quad * 8;
            short8 b0 = *(const short8*)(kp);
            short8 b1 = *(const short8*)(kp + 32);
            s[h2] = __builtin_amdgcn_mfma_f32_16x16x32_bf16(aq0, b0, s[h2], 0, 0, 0);
            s[h2] = __builtin_amdgcn_mfma_f32_16x16x32_bf16(aq1, b1, s[h2], 0, 0, 0);
        }

        // ---- scale + causal mask ----
        const bool need_mask = (kk0 + 31 > q0);
#pragma unroll
        for (int h2 = 0; h2 < 2; ++h2) {
#pragma unroll
            for (int r = 0; r < 4; ++r) {
                float v = s[h2][r] * 0.125f;   // 1/sqrt(64)
                if (need_mask) {
                    int kg = kk0 + h2 * 16 + col;
                    int qg = q0 + quad * 4 + r;
                    if (kg > qg) v -= 10000.0f;
                }
                s[h2][r] = v;
            }
        }

        // ---- online softmax ----
        float mx[4], sm[4];
#pragma unroll
        for (int r = 0; r < 4; ++r) mx[r] = fmaxf(s[0][r], s[1][r]);
#pragma unroll
        for (int d = 1; d < 16; d <<= 1) {
#pragma unroll
            for (int r = 0; r < 4; ++r) mx[r] = fmaxf(mx[r], __shfl_xor(mx[r], d));
        }
        float alpha[4];
#pragma unroll
        for (int r = 0; r < 4; ++r) {
            float mn = fmaxf(m_i[r], mx[r]);
            alpha[r] = __expf(m_i[r] - mn);
            m_i[r] = mn;
        }
#pragma unroll
        for (int r = 0; r < 4; ++r) {
            s[0][r] = __expf(s[0][r] - m_i[r]);
            s[1][r] = __expf(s[1][r] - m_i[r]);
            sm[r] = s[0][r] + s[1][r];
        }
#pragma unroll
        for (int d = 1; d < 16; d <<= 1) {
#pragma unroll
            for (int r = 0; r < 4; ++r) sm[r] += __shfl_xor(sm[r], d);
        }
#pragma unroll
        for (int r = 0; r < 4; ++r) l_i[r] = l_i[r] * alpha[r] + sm[r];

        // ---- P: C-layout -> A-layout via LDS ----
#pragma unroll
        for (int h2 = 0; h2 < 2; ++h2) {
#pragma unroll
            for (int r = 0; r < 4; ++r)
                pbuf[quad * 4 + r][h2 * 16 + col] = f2bf(s[h2][r]);
        }
        __syncthreads();
        short8 apf = *(const short8*)(&pbuf[col][quad * 8]);
        __syncthreads();

        // ---- rescale O, then PV ----
#pragma unroll
        for (int t2 = 0; t2 < 4; ++t2) {
#pragma unroll
            for (int r = 0; r < 4; ++r) o[t2][r] *= alpha[r];
        }
#pragma unroll
        for (int t2 = 0; t2 < 4; ++t2) {
            short8 bv = *(const short8*)(VT + vtb + (size_t)(t2 * 16 + col) * SS + kk0 + quad * 8);
            o[t2] = __builtin_amdgcn_mfma_f32_16x16x32_bf16(apf, bv, o[t2], 0, 0, 0);
        }
    }

    // ---- epilogue: normalize, merge heads, write [B,S,D] bf16 ----
    const int b = bh >> 4, h = bh & 15;
#pragma unroll
    for (int r = 0; r < 4; ++r) {
        const float rinv = 1.0f / l_i[r];
        const int srow = q0 + quad * 4 + r;
#pragma unroll
        for (int t2 = 0; t2 < 4; ++t2) {
            size_t idx = ((size_t)b * SS + srow) * DD + h * DH + t2 * 16 + col;
            AO[idx] = f2bf(o[t2][r] * rinv);
        }
    }
}

// ============================================================
extern "C" void kernel_launch(void* const* d_in, const int* in_sizes, int n_in,
                              void* d_out, int out_size, void* d_ws, size_t ws_size,
                              hipStream_t stream)
{
    const float* x_q  = (const float*)d_in[0];
    const float* x_kv = (const float*)d_in[1];
    const float* Wq   = (const float*)d_in[2];
    const float* bq   = (const float*)d_in[3];
    const float* Wk   = (const float*)d_in[4];
    const float* bk   = (const float*)d_in[5];
    const float* Wv   = (const float*)d_in[6];
    const float* bv   = (const float*)d_in[7];
    const float* Wo   = (const float*)d_in[8];
    const float* bo   = (const float*)d_in[9];

    const size_t elems = (size_t)BB * HH * SS * DH;   // 8,388,608 bf16 per buffer
    // Q lives in d_out's fp32 region (33.5 MB >= 16.8 MB needed); safe because
    // the final projection (which overwrites d_out) runs after attention.
    ushort_t* Qb  = (ushort_t*)d_out;
    ushort_t* Kb  = (ushort_t*)d_ws;
    ushort_t* VTb = Kb + elems;
    ushort_t* AOb = VTb + elems;

    dim3 blk(64);
    dim3 gproj(DD / 64, MM / 16);   // 16 x 512

    proj_a32<0><<<gproj, blk, 0, stream>>>(x_q,  Wq, bq, Qb);
    proj_a32<0><<<gproj, blk, 0, stream>>>(x_kv, Wk, bk, Kb);
    proj_a32<1><<<gproj, blk, 0, stream>>>(x_kv, Wv, bv, VTb);

    attn_kernel<<<dim3(BB * HH * (SS / 16)), blk, 0, stream>>>(Qb, Kb, VTb, AOb);

    proj_o32<<<gproj, blk, 0, stream>>>(AOb, Wo, bo, (float*)d_out);
}

// Round 3
// 700.448 us; speedup vs baseline: 2.1715x; 2.1715x over previous
//
#include <hip/hip_runtime.h>

typedef short short8 __attribute__((ext_vector_type(8)));
typedef float f32x4 __attribute__((ext_vector_type(4)));
typedef unsigned short ushort_t;

// ---- constants (problem is fixed-shape) ----
#define BB 4
#define SS 2048
#define DD 1024
#define HH 16
#define DH 64
#define KK 1024
#define MM (BB*SS)          // 8192 rows
#define E_X (MM*DD)         // 8,388,608 elems
#define E_W (DD*DD)         // 1,048,576 elems

static __device__ __forceinline__ ushort_t f2bf(float f) {
    unsigned u = __builtin_bit_cast(unsigned, f);
    u = u + 0x7fff + ((u >> 16) & 1);   // RNE
    return (ushort_t)(u >> 16);
}
static __device__ __forceinline__ short8 ld_cvt8(const float* __restrict__ p) {
    const f32x4* q = (const f32x4*)p;
    f32x4 a = q[0], b = q[1];
    short8 r;
    r[0] = (short)f2bf(a[0]); r[1] = (short)f2bf(a[1]);
    r[2] = (short)f2bf(a[2]); r[3] = (short)f2bf(a[3]);
    r[4] = (short)f2bf(b[0]); r[5] = (short)f2bf(b[1]);
    r[6] = (short)f2bf(b[2]); r[7] = (short)f2bf(b[3]);
    return r;
}
static __device__ __forceinline__ void gld16(const ushort_t* g, ushort_t* l) {
    __builtin_amdgcn_global_load_lds(
        (const __attribute__((address_space(1))) unsigned int*)g,
        (__attribute__((address_space(3))) unsigned int*)l, 16, 0, 0);
}

// ============================================================
// Fused fp32 -> bf16 conversion for X_q, X_kv, Wq, Wk, Wv, Wo
// ============================================================
#define GX (E_X/8)   // 1,048,576 groups of 8
#define GW (E_W/8)   // 131,072
__global__ __launch_bounds__(256)
void cvt_all(const float* __restrict__ xq, const float* __restrict__ xkv,
             const float* __restrict__ wq, const float* __restrict__ wk,
             const float* __restrict__ wv, const float* __restrict__ wo,
             ushort_t* xq16, ushort_t* xkv16,
             ushort_t* wq16, ushort_t* wk16, ushort_t* wv16, ushort_t* wo16)
{
    size_t g = (size_t)blockIdx.x * 256 + threadIdx.x;
    const float* src; ushort_t* dst; size_t off;
    if (g < (size_t)GX)            { src = xq;  dst = xq16;  off = g; }
    else if (g < 2*(size_t)GX)     { src = xkv; dst = xkv16; off = g - GX; }
    else {
        size_t gg = g - 2*(size_t)GX;
        int wi = (int)(gg >> 17);          // / GW
        off = gg & (GW - 1);
        src = (wi==0)? wq : (wi==1)? wk : (wi==2)? wv : wo;
        dst = (wi==0)? wq16 : (wi==1)? wk16 : (wi==2)? wv16 : wo16;
    }
    *(short8*)(dst + off*8) = ld_cvt8(src + off*8);
}

// ============================================================
// m97-style GEMM: C[128,128] = A[M,K](bf16) @ Bw[N,K]^T(bf16) + bias(fp32)
// 256 threads = 4 waves, each wave a 64x64 quadrant (4x4 of 16x16 MFMA).
// MODE 0: out bf16 [B,H,S,dh]; MODE 1: bf16 [B,H,dh,S]; MODE 2: fp32 [M,N].
// ============================================================
template<int MODE>
__global__ __launch_bounds__(256)
void gemm_bt(const ushort_t* __restrict__ A, const ushort_t* __restrict__ Bw,
             const float* __restrict__ bias, void* __restrict__ outv)
{
    __shared__ ushort_t As[128*32];
    __shared__ ushort_t Bs[128*32];

    const int tid  = threadIdx.x;
    const int lane = tid & 63;
    const int wave = tid >> 6;
    const int wr = wave >> 1, wc = wave & 1;
    const int quad = lane >> 4, col = lane & 15;
    const int n0 = blockIdx.x * 128;
    const int m0 = blockIdx.y * 128;

    const int r0 = tid >> 2;           // staging row (0..63)
    const int kc = (tid & 3) * 8;      // staging k-offset

    f32x4 acc[4][4] = {};

    for (int k0 = 0; k0 < KK; k0 += 32) {
        gld16(A  + (size_t)(m0 + r0)      * KK + k0 + kc, As + tid*8);
        gld16(A  + (size_t)(m0 + 64 + r0) * KK + k0 + kc, As + 2048 + tid*8);
        gld16(Bw + (size_t)(n0 + r0)      * KK + k0 + kc, Bs + tid*8);
        gld16(Bw + (size_t)(n0 + 64 + r0) * KK + k0 + kc, Bs + 2048 + tid*8);
        __syncthreads();

        short8 af[4], bf[4];
#pragma unroll
        for (int i = 0; i < 4; ++i)
            af[i] = *(const short8*)(As + (wr*64 + i*16 + col)*32 + quad*8);
#pragma unroll
        for (int j = 0; j < 4; ++j)
            bf[j] = *(const short8*)(Bs + (wc*64 + j*16 + col)*32 + quad*8);
#pragma unroll
        for (int i = 0; i < 4; ++i)
#pragma unroll
            for (int j = 0; j < 4; ++j)
                acc[i][j] = __builtin_amdgcn_mfma_f32_16x16x32_bf16(af[i], bf[j], acc[i][j], 0, 0, 0);
        __syncthreads();
    }

#pragma unroll
    for (int j = 0; j < 4; ++j) {
        const int n = n0 + wc*64 + j*16 + col;
        const float bv = bias[n];
#pragma unroll
        for (int i = 0; i < 4; ++i) {
#pragma unroll
            for (int r = 0; r < 4; ++r) {
                const int m = m0 + wr*64 + i*16 + quad*4 + r;
                const float v = acc[i][j][r] + bv;
                if (MODE == 2) {
                    ((float*)outv)[(size_t)m * DD + n] = v;
                } else {
                    int b = m >> 11, s = m & (SS-1);
                    int h = n >> 6,  d = n & (DH-1);
                    size_t idx = (MODE == 0)
                        ? ((size_t)(b*HH + h) * SS + s) * DH + d
                        : ((size_t)(b*HH + h) * DH + d) * SS + s;
                    ((ushort_t*)outv)[idx] = f2bf(v);
                }
            }
        }
    }
}

// ============================================================
// Flash attention: 256-thread blocks = 4 waves = 4 consecutive 16-query
// tiles of one (b,h). 64-key steps. All waves have IDENTICAL trip counts
// (4 q-tiles span exactly one 64-key tile), so __syncthreads is legal.
// Q,K: [BH,S,64] bf16.  VT: [BH,64,S] bf16.  AO: [B,S,D] bf16.
// ============================================================
__global__ __launch_bounds__(256)
void attn_kernel(const ushort_t* __restrict__ Q,
                 const ushort_t* __restrict__ Km,
                 const ushort_t* __restrict__ VT,
                 ushort_t* __restrict__ AO)
{
    __shared__ alignas(16) ushort_t pbuf[4][16][64];   // per-wave P tile

    const int tid  = threadIdx.x;
    const int lane = tid & 63;
    const int wave = tid >> 6;
    const int quad = lane >> 4;
    const int col  = lane & 15;

    const int blk = blockIdx.x;        // 2048 blocks
    const int bh  = blk >> 5;          // 32 blocks per (b,h)
    const int qt  = (blk & 31) * 4 + wave;
    const int q0  = qt * 16;
    const int ntiles = (blk & 31) + 1; // same for all 4 waves

    const size_t qkb = (size_t)bh * SS * DH;
    const size_t vtb = (size_t)bh * DH * SS;

    const ushort_t* qp = Q + qkb + (size_t)(q0 + col) * DH + quad * 8;
    short8 aq0 = *(const short8*)(qp);
    short8 aq1 = *(const short8*)(qp + 32);

    f32x4 o[4] = {};
    float m_i[4] = {-1e30f, -1e30f, -1e30f, -1e30f};
    float l_i[4] = {};

    for (int tt = 0; tt < ntiles; ++tt) {
        const int kk0 = tt * 64;

        // ---- QK^T over 64 keys (4 x 16-key quarters) ----
        f32x4 s[4] = {};
#pragma unroll
        for (int h4 = 0; h4 < 4; ++h4) {
            const ushort_t* kp = Km + qkb + (size_t)(kk0 + h4*16 + col) * DH + quad * 8;
            short8 b0 = *(const short8*)(kp);
            short8 b1 = *(const short8*)(kp + 32);
            s[h4] = __builtin_amdgcn_mfma_f32_16x16x32_bf16(aq0, b0, s[h4], 0, 0, 0);
            s[h4] = __builtin_amdgcn_mfma_f32_16x16x32_bf16(aq1, b1, s[h4], 0, 0, 0);
        }

        // ---- scale + causal mask ----
        const bool need_mask = (kk0 + 63 > q0);
#pragma unroll
        for (int h4 = 0; h4 < 4; ++h4) {
#pragma unroll
            for (int r = 0; r < 4; ++r) {
                float v = s[h4][r] * 0.125f;     // 1/sqrt(64)
                if (need_mask) {
                    int kg = kk0 + h4*16 + col;
                    int qg = q0 + quad*4 + r;
                    if (kg > qg) v -= 10000.0f;
                }
                s[h4][r] = v;
            }
        }

        // ---- online softmax ----
        float mx[4], sm[4];
#pragma unroll
        for (int r = 0; r < 4; ++r)
            mx[r] = fmaxf(fmaxf(s[0][r], s[1][r]), fmaxf(s[2][r], s[3][r]));
#pragma unroll
        for (int d = 1; d < 16; d <<= 1) {
#pragma unroll
            for (int r = 0; r < 4; ++r) mx[r] = fmaxf(mx[r], __shfl_xor(mx[r], d));
        }
        float alpha[4];
#pragma unroll
        for (int r = 0; r < 4; ++r) {
            float mn = fmaxf(m_i[r], mx[r]);
            alpha[r] = __expf(m_i[r] - mn);
            m_i[r] = mn;
        }
#pragma unroll
        for (int r = 0; r < 4; ++r) {
            s[0][r] = __expf(s[0][r] - m_i[r]);
            s[1][r] = __expf(s[1][r] - m_i[r]);
            s[2][r] = __expf(s[2][r] - m_i[r]);
            s[3][r] = __expf(s[3][r] - m_i[r]);
            sm[r] = (s[0][r] + s[1][r]) + (s[2][r] + s[3][r]);
        }
#pragma unroll
        for (int d = 1; d < 16; d <<= 1) {
#pragma unroll
            for (int r = 0; r < 4; ++r) sm[r] += __shfl_xor(sm[r], d);
        }
#pragma unroll
        for (int r = 0; r < 4; ++r) l_i[r] = l_i[r] * alpha[r] + sm[r];

        // ---- P: C-layout -> A-layout via per-wave LDS ----
#pragma unroll
        for (int h4 = 0; h4 < 4; ++h4) {
#pragma unroll
            for (int r = 0; r < 4; ++r)
                pbuf[wave][quad*4 + r][h4*16 + col] = f2bf(s[h4][r]);
        }
        __syncthreads();
        short8 apf0 = *(const short8*)(&pbuf[wave][col][quad*8]);
        short8 apf1 = *(const short8*)(&pbuf[wave][col][32 + quad*8]);
        __syncthreads();

        // ---- rescale O, then PV (two K=32 halves) ----
#pragma unroll
        for (int j = 0; j < 4; ++j) {
#pragma unroll
            for (int r = 0; r < 4; ++r) o[j][r] *= alpha[r];
        }
#pragma unroll
        for (int j = 0; j < 4; ++j) {
            const ushort_t* vp = VT + vtb + (size_t)(j*16 + col) * SS + kk0 + quad*8;
            short8 v0 = *(const short8*)(vp);
            short8 v1 = *(const short8*)(vp + 32);
            o[j] = __builtin_amdgcn_mfma_f32_16x16x32_bf16(apf0, v0, o[j], 0, 0, 0);
            o[j] = __builtin_amdgcn_mfma_f32_16x16x32_bf16(apf1, v1, o[j], 0, 0, 0);
        }
    }

    // ---- epilogue: normalize, merge heads, write [B,S,D] bf16 ----
    const int b = bh >> 4, h = bh & 15;
#pragma unroll
    for (int r = 0; r < 4; ++r) {
        const float rinv = 1.0f / l_i[r];
        const int srow = q0 + quad*4 + r;
#pragma unroll
        for (int j = 0; j < 4; ++j) {
            size_t idx = ((size_t)b * SS + srow) * DD + h * DH + j*16 + col;
            AO[idx] = f2bf(o[j][r] * rinv);
        }
    }
}

// ============================================================
extern "C" void kernel_launch(void* const* d_in, const int* in_sizes, int n_in,
                              void* d_out, int out_size, void* d_ws, size_t ws_size,
                              hipStream_t stream)
{
    const float* x_q  = (const float*)d_in[0];
    const float* x_kv = (const float*)d_in[1];
    const float* Wq   = (const float*)d_in[2];
    const float* bq   = (const float*)d_in[3];
    const float* Wk   = (const float*)d_in[4];
    const float* bk   = (const float*)d_in[5];
    const float* Wv   = (const float*)d_in[6];
    const float* bv   = (const float*)d_in[7];
    const float* Wo   = (const float*)d_in[8];
    const float* bo   = (const float*)d_in[9];

    // ws layout (bf16 elems), lifetime-aliased:
    //   buf1: Xq16  -> Kb      buf2: Xkv16 -> AOb      buf3: VTb
    //   + 4 bf16 weight copies.  Total = 3*E_X + 4*E_W elems = 58.7 MB.
    ushort_t* buf1 = (ushort_t*)d_ws;
    ushort_t* buf2 = buf1 + E_X;
    ushort_t* buf3 = buf2 + E_X;
    ushort_t* Wq16 = buf3 + E_X;
    ushort_t* Wk16 = Wq16 + E_W;
    ushort_t* Wv16 = Wk16 + E_W;
    ushort_t* Wo16 = Wv16 + E_W;
    // Q (bf16, 16.8 MB) parked in d_out (33.5 MB fp32); read by attention,
    // overwritten only by the final projection afterwards.
    ushort_t* Qb = (ushort_t*)d_out;

    dim3 blk(256);

    cvt_all<<<dim3((2*GX + 4*GW)/256), blk, 0, stream>>>(
        x_q, x_kv, Wq, Wk, Wv, Wo, buf1, buf2, Wq16, Wk16, Wv16, Wo16);

    dim3 gproj(DD/128, MM/128);   // 8 x 64
    gemm_bt<0><<<gproj, blk, 0, stream>>>(buf1, Wq16, bq, Qb);     // Q
    gemm_bt<0><<<gproj, blk, 0, stream>>>(buf2, Wk16, bk, buf1);   // K (over Xq16)
    gemm_bt<1><<<gproj, blk, 0, stream>>>(buf2, Wv16, bv, buf3);   // V^T

    attn_kernel<<<dim3(BB*HH*(SS/64)), blk, 0, stream>>>(Qb, buf1, buf3, buf2);

    gemm_bt<2><<<gproj, blk, 0, stream>>>(buf2, Wo16, bo, d_out);  // final proj
}